// Round 4
// baseline (81.794 us; speedup 1.0000x reference)
//
#include <hip/hip_runtime.h>
#include <math.h>

// Problem constants (fixed by the reference's setup_inputs)
#define BB 32
#define LL 40
#define HH 448
#define SS 8000
#define NC 25
#define H4 (HH / 4)     // 112 float4 per row
#define NBLK (SS / 4)   // 2000 score blocks, 4 waves (segments) each
#define CHUNK 5         // candidates per software-pipelined chunk

// Native Clang vector (works with __builtin_nontemporal_load, unlike HIP float4)
typedef float f4 __attribute__((ext_vector_type(4)));

// ---------------- Kernel 1: x_pool[b,k] = sum_{l,h} x[b,l,h] * W[k,h] ----------------
// grid: (BB, 14). Phase-1 pools x[b] over L (redundant per k-chunk block, L2-hot).
// Phase-2: 32 k per block, 8 lanes cooperate per k -> 14-deep load ILP.
__global__ __launch_bounds__(256) void pool_kernel(const float* __restrict__ x,
                                                   const float* __restrict__ W,
                                                   float* __restrict__ xpool) {
    __shared__ float xsum[HH];
    const int b = blockIdx.x;
    const int kc = blockIdx.y;
    const int tid = threadIdx.x;
    const float* xb = x + (size_t)b * LL * HH;

    // Phase 1: pool over L (coalesced: consecutive threads -> consecutive h)
    for (int h = tid; h < HH; h += 256) {
        float s = 0.f;
        #pragma unroll 8
        for (int l = 0; l < LL; ++l) s += xb[(size_t)l * HH + h];
        xsum[h] = s;
    }
    __syncthreads();

    // Phase 2: 32 k-values per block; 8 lanes cooperate on each k.
    const int kk  = tid >> 3;          // 0..31  (k within chunk)
    const int sub = tid & 7;           // 0..7   (lane within octet)
    const int k   = kc * 32 + kk;
    const f4* wr = (const f4*)(W + (size_t)k * HH);
    float acc = 0.f;
    #pragma unroll 14
    for (int j = sub; j < H4; j += 8) {   // 14 independent iterations
        f4 w4 = wr[j];
        acc += xsum[j * 4 + 0] * w4.x;
        acc += xsum[j * 4 + 1] * w4.y;
        acc += xsum[j * 4 + 2] * w4.z;
        acc += xsum[j * 4 + 3] * w4.w;
    }
    // reduce across the octet (sub = 0..7)
    acc += __shfl_xor(acc, 1, 64);
    acc += __shfl_xor(acc, 2, 64);
    acc += __shfl_xor(acc, 4, 64);
    if (sub == 0) xpool[b * HH + k] = acc;
}

// ---------------- Kernel 2: one wave per segment; chunked scores + online softmax ----------------
__global__ __launch_bounds__(256) void score_kernel(
        const float* __restrict__ cand,
        const float* __restrict__ xpool,
        const int* __restrict__ batch_idx,
        const int* __restrict__ label_in_seg,
        float2* __restrict__ blk_part) {
    __shared__ float s_loss[4];
    __shared__ float s_acc[4];
    const int wave = threadIdx.x >> 6;
    const int lane = threadIdx.x & 63;
    const int seg = blockIdx.x * 4 + wave;   // SS = 4 * gridDim.x exactly

    const int label = label_in_seg[seg];
    const long t0 = (long)seg * NC;

    float m = -INFINITY;
    float ssum = 0.f;
    float label_score = 0.f;

    #pragma unroll 1
    for (int cc = 0; cc < NC; cc += CHUNK) {
        float sc[CHUNK];
        // Streaming phase: 2*CHUNK independent loads in flight
        #pragma unroll
        for (int u = 0; u < CHUNK; ++u) {
            const long t = t0 + cc + u;
            const int bi = batch_idx[t];
            const f4* cr = (const f4*)(cand + t * (long)HH);
            const f4* xr = (const f4*)(xpool + bi * HH);
            f4 a = __builtin_nontemporal_load(cr + lane);   // streamed once
            f4 b = xr[lane];                                // L2-hot
            float p = a.x * b.x + a.y * b.y + a.z * b.z + a.w * b.w;
            if (lane < 48) {
                f4 a2 = __builtin_nontemporal_load(cr + 64 + lane);
                f4 b2 = xr[64 + lane];
                p += a2.x * b2.x + a2.y * b2.y + a2.z * b2.z + a2.w * b2.w;
            }
            sc[u] = p;
        }
        // Reduction phase: CHUNK independent butterfly chains
        #pragma unroll
        for (int off = 32; off > 0; off >>= 1) {
            #pragma unroll
            for (int u = 0; u < CHUNK; ++u) sc[u] += __shfl_xor(sc[u], off, 64);
        }
        // Softmax update once per chunk
        float cmax = fmaxf(fmaxf(fmaxf(sc[0], sc[1]), fmaxf(sc[2], sc[3])), sc[4]);
        const float nm = fmaxf(m, cmax);
        float add = __expf(sc[0] - nm) + __expf(sc[1] - nm) + __expf(sc[2] - nm)
                  + __expf(sc[3] - nm) + __expf(sc[4] - nm);
        ssum = ssum * __expf(m - nm) + add;
        m = nm;
        #pragma unroll
        for (int u = 0; u < CHUNK; ++u)
            if (cc + u == label) label_score = sc[u];
    }

    if (lane == 0) {
        const float lse = m + __logf(ssum);
        s_loss[wave] = lse - label_score;
        s_acc[wave] = (label_score >= m) ? 1.f : 0.f;
    }
    __syncthreads();
    if (threadIdx.x == 0) {
        blk_part[blockIdx.x] = make_float2(
            (s_loss[0] + s_loss[1]) + (s_loss[2] + s_loss[3]),
            (s_acc[0] + s_acc[1]) + (s_acc[2] + s_acc[3]));
    }
}

// ---------------- Kernel 3: single-wave, barrier-free final reduction ----------------
__global__ void reduce_kernel(const float2* __restrict__ blk_part,
                              float* __restrict__ out) {
    const int lane = threadIdx.x;   // 64 threads
    float l = 0.f, a = 0.f;
    for (int s = lane; s < NBLK; s += 64) {
        float2 v = blk_part[s];
        l += v.x;
        a += v.y;
    }
    #pragma unroll
    for (int off = 32; off > 0; off >>= 1) {
        l += __shfl_xor(l, off, 64);
        a += __shfl_xor(a, off, 64);
    }
    if (lane == 0) {
        out[0] = l / (float)BB;   // loss = sum(lse - label_score) / nbatch
        out[1] = a / (float)SS;   // acc  = mean(label >= seg_max)
    }
}

extern "C" void kernel_launch(void* const* d_in, const int* in_sizes, int n_in,
                              void* d_out, int out_size, void* d_ws, size_t ws_size,
                              hipStream_t stream) {
    const float* x_mol   = (const float*)d_in[0];   // [32,40,448] f32
    const float* cand    = (const float*)d_in[1];   // [200000,448] f32
    const float* W       = (const float*)d_in[2];   // [448,448] f32
    const int*   bidx    = (const int*)d_in[3];     // [200000] i32
    const int*   label   = (const int*)d_in[4];     // [8000] i32
    float* out = (float*)d_out;                     // [loss, acc]

    // Workspace layout: xpool[32*448] floats | blk_part[2000] float2
    float* ws        = (float*)d_ws;
    float* xpool     = ws;                          // 14336 floats (57344 B, 8B-aligned end)
    float2* blk_part = (float2*)(ws + BB * HH);     // 2000 float2

    dim3 pgrid(BB, 14);
    pool_kernel<<<pgrid, 256, 0, stream>>>(x_mol, W, xpool);
    score_kernel<<<NBLK, 256, 0, stream>>>(cand, xpool, bidx, label, blk_part);
    reduce_kernel<<<1, 64, 0, stream>>>(blk_part, out);
}